// Round 15
// baseline (131.086 us; speedup 1.0000x reference)
//
#include <hip/hip_runtime.h>

// CausalSelfAttention: B=4 T=2048 D=768 NH=12 DH=64, fp32 in/out, bf16 MFMA compute.
// v15: = v14 with attn reworked to 64 q-rows/WAVE (2 x 32-row halves): each K/V
// fragment is read from LDS once and feeds MFMAs for BOTH halves -> LDS reads,
// staging bytes, barriers, and block count per FLOP all halve (768 -> 384 blocks).
// Dead half1 subtiles skipped by uniform branch. GEMMs/cvt = v14 exact.

#define B_ 4
#define T_ 2048
#define D_ 768
#define NH_ 12
#define DH_ 64
#define M_ (B_ * T_)  // 8192

typedef __attribute__((ext_vector_type(8))) short bf16x8;    // 8 bf16 = 4 VGPRs
typedef __attribute__((ext_vector_type(4))) float f32x4;
typedef __attribute__((ext_vector_type(16))) float f32x16;
typedef __attribute__((ext_vector_type(4))) unsigned int u32x4;

__device__ __forceinline__ unsigned short f2bf(float f) {
  unsigned int u = __builtin_bit_cast(unsigned int, f);
  u += 0x7FFFu + ((u >> 16) & 1u);  // RNE
  return (unsigned short)(u >> 16);
}

__device__ __forceinline__ void async16(const void* g, void* l) {
  // global->LDS DMA, 16B/lane; LDS dest = wave-uniform base + lane*16 (m97/m104)
  __builtin_amdgcn_global_load_lds(
      (const __attribute__((address_space(1))) unsigned int*)g,
      (__attribute__((address_space(3))) unsigned int*)l, 16, 0, 0);
}

// raw barrier with compiler-level memory fence (no vmcnt drain, unlike __syncthreads)
#define RAW_BARRIER()                         \
  do {                                        \
    asm volatile("" ::: "memory");            \
    __builtin_amdgcn_s_barrier();             \
    asm volatile("" ::: "memory");            \
  } while (0)

// ---------------------------------------------------------------- cvt fp32->bf16
__global__ void cvt_kernel(const float* __restrict__ x, const float* __restrict__ wq,
                           const float* __restrict__ wk, const float* __restrict__ wv,
                           const float* __restrict__ wo,
                           unsigned short* __restrict__ xb, unsigned short* __restrict__ wqb,
                           unsigned short* __restrict__ wkb, unsigned short* __restrict__ wvb,
                           unsigned short* __restrict__ wob) {
  const float* src; unsigned short* dst; int n4;
  switch (blockIdx.y) {
    case 0: src = x;  dst = xb;  n4 = M_ * D_ / 4; break;
    case 1: src = wq; dst = wqb; n4 = D_ * D_ / 4; break;
    case 2: src = wk; dst = wkb; n4 = D_ * D_ / 4; break;
    case 3: src = wv; dst = wvb; n4 = D_ * D_ / 4; break;
    default: src = wo; dst = wob; n4 = D_ * D_ / 4; break;
  }
  int stride = gridDim.x * blockDim.x;
  for (int i = blockIdx.x * blockDim.x + threadIdx.x; i < n4; i += stride) {
    float4 v = ((const float4*)src)[i];
    ushort4 o;
    o.x = f2bf(v.x); o.y = f2bf(v.y); o.z = f2bf(v.z); o.w = f2bf(v.w);
    ((ushort4*)dst)[i] = o;
  }
}

// ---------------------------------------------------------------- bf16 GEMM (B^T input)
// v9 exact: 128x256 tile, BK=32, 8 waves; 3 LDS slots x 24KB; depth-2 counted-vmcnt.
__global__ __launch_bounds__(512, 4) void gemm_kernel(
    const unsigned short* __restrict__ A,
    const unsigned short* __restrict__ W0, const unsigned short* __restrict__ W1,
    const unsigned short* __restrict__ W2,
    const float* __restrict__ bias0, const float* __restrict__ bias1,
    const float* __restrict__ bias2,
    void* out0, void* out1, void* out2,
    float s0, int K, int qkv) {
  __shared__ __align__(16) char lds[73728];   // 3 slots x 24576 (A@0, B@8192)

  int bid = blockIdx.x;
  int xcd = bid & 7, g = bid >> 3;
  int mt, nt;
  if (qkv) { mt = xcd + (g / 9) * 8; nt = g % 9; }
  else     { mt = xcd + (g / 3) * 8;  nt = g % 3; }
  int y  = qkv ? nt / 3 : 0;
  int nW = qkv ? nt % 3 : nt;            // 256-col tile within the 768-wide region
  const unsigned short* W = y == 0 ? W0 : (y == 1 ? W1 : W2);
  const float* bias = y == 0 ? bias0 : (y == 1 ? bias1 : bias2);
  void* outp = y == 0 ? out0 : (y == 1 ? out1 : out2);
  float scl = (qkv && y == 0) ? s0 : 1.0f;
  int mode = qkv ? ((y == 2) ? 2 : 1) : 0;

  int tid = threadIdx.x, lane = tid & 63, wid = tid >> 6;
  int l15 = lane & 15, l4 = lane >> 4;
  int wm = wid >> 2, wn = wid & 3;
  int m0 = mt << 7, n0w = nW << 8;       // n0w in [0,768)

  int aRow, aCol;
  {
    int row = wid * 16 + (lane >> 2);
    int colE = (lane & 3) * 8;
    aRow = row;
    aCol = colE ^ (((row >> 1) & 3) << 3);
  }
  int bRow[2], bCol[2];
#pragma unroll
  for (int c = 0; c < 2; ++c) {
    int u = c * 8 + wid;
    int row = u * 16 + (lane >> 2);
    int colE = (lane & 3) * 8;
    bRow[c] = row;
    bCol[c] = colE ^ (((row >> 1) & 3) << 3);
  }

  int aoff[4], boff[4];
#pragma unroll
  for (int mf = 0; mf < 4; ++mf) {
    int row = wm * 64 + mf * 16 + l15;
    aoff[mf] = row * 64 + ((l4 * 16) ^ (((row >> 1) & 3) << 4));
  }
#pragma unroll
  for (int nf = 0; nf < 4; ++nf) {
    int row = wn * 64 + nf * 16 + l15;
    boff[nf] = 8192 + row * 64 + ((l4 * 16) ^ (((row >> 1) & 3) << 4));
  }

  const unsigned short* Wb = W + (size_t)n0w * K;   // 256-row W panel

#define ISSUE_TILE(kt, slot)                                                       \
  do {                                                                             \
    async16(A + (size_t)(m0 + aRow) * K + (kt) + aCol, (slot) + wid * 1024);       \
    _Pragma("unroll") for (int c = 0; c < 2; ++c)                                  \
      async16(Wb + (size_t)bRow[c] * K + (kt) + bCol[c],                           \
              (slot) + 8192 + (c * 8 + wid) * 1024);                               \
  } while (0)

  f32x4 acc[4][4] = {};
  char* b0 = lds;             // compute slot (tile t)
  char* b1 = lds + 24576;     // tile t+1 (in flight)
  char* b2 = lds + 49152;     // issue target (tile t+2)

  ISSUE_TILE(0, b0);
  ISSUE_TILE(32, b1);

  int NT = K >> 5;   // 24
#pragma unroll 1
  for (int t = 0; t < NT; ++t) {
    if (t + 1 < NT) asm volatile("s_waitcnt vmcnt(3)" ::: "memory");  // tile t landed
    else            asm volatile("s_waitcnt vmcnt(0)" ::: "memory");  // tail drain
    RAW_BARRIER();   // all waves: tile t visible; slot b2 (tile t-1) free
    if (t + 2 < NT) ISSUE_TILE((t + 2) << 5, b2);
    bf16x8 af[4], bfr[4];
#pragma unroll
    for (int mf = 0; mf < 4; ++mf) af[mf] = *(const bf16x8*)(b0 + aoff[mf]);
#pragma unroll
    for (int nf = 0; nf < 4; ++nf) bfr[nf] = *(const bf16x8*)(b0 + boff[nf]);
    __builtin_amdgcn_s_setprio(1);
#pragma unroll
    for (int mf = 0; mf < 4; ++mf)
#pragma unroll
      for (int nf = 0; nf < 4; ++nf)
        acc[mf][nf] = __builtin_amdgcn_mfma_f32_16x16x32_bf16(af[mf], bfr[nf], acc[mf][nf], 0, 0, 0);
    __builtin_amdgcn_s_setprio(0);
    char* tmp = b0; b0 = b1; b1 = b2; b2 = tmp;   // rotate slots
  }
#undef ISSUE_TILE

  // epilogue
  if (mode == 2) {
#pragma unroll
    for (int nf = 0; nf < 4; ++nf) {
      int colW = n0w + wn * 64 + nf * 16 + l15;   // = h*DH + d
      float bv = bias[colW];
      int h = colW >> 6, d = colW & 63;
#pragma unroll
      for (int mf = 0; mf < 4; ++mf) {
        int rbase = m0 + wm * 64 + mf * 16 + l4 * 4;   // = b*T + t
        int bb = rbase >> 11, tt = rbase & (T_ - 1);
        ushort4 o;
        o.x = f2bf(acc[mf][nf][0] + bv);
        o.y = f2bf(acc[mf][nf][1] + bv);
        o.z = f2bf(acc[mf][nf][2] + bv);
        o.w = f2bf(acc[mf][nf][3] + bv);
        *(ushort4*)((unsigned short*)outp + ((size_t)(bb * NH_ + h) * DH_ + d) * T_ + tt) = o;
      }
    }
  } else {
#pragma unroll
    for (int nf = 0; nf < 4; ++nf) {
      int colW = n0w + wn * 64 + nf * 16 + l15;
      float bv = bias[colW];
#pragma unroll
      for (int mf = 0; mf < 4; ++mf) {
        int rbase = m0 + wm * 64 + mf * 16 + l4 * 4;
#pragma unroll
        for (int r = 0; r < 4; ++r) {
          float v = (acc[mf][nf][r] + bv) * scl;
          size_t idx = (size_t)(rbase + r) * D_ + colW;
          if (mode == 1) ((unsigned short*)outp)[idx] = f2bf(v);
          else           ((float*)outp)[idx] = v;
        }
      }
    }
  }
}

// ---------------------------------------------------------------- flash attention v15
// Block = q-tile of 256 rows; 4 waves; each wave owns 64 q-rows as two 32-row halves
// (qrow1 = q0+w*32+l31, qrow2 = qrow1+128). Each K/V LDS fragment is read ONCE and
// feeds MFMAs for both halves. Paired-KV staging as v14 (4 K + 4 V bufs, 64KB,
// barrier+stage at even t). Dead half1 subtiles (t >= 4qt+2) skipped uniformly.
// Mask: half1 at t >= 4qt, half2 at t >= 4qt+2. Softmax per-n to cap VGPR liveness.
// Grid 384 = 8 xcd x (8 qt desc x 6 heads).
__global__ __launch_bounds__(256, 2) void attn_kernel(
    const unsigned short* __restrict__ Q, const unsigned short* __restrict__ Kg,
    const unsigned short* __restrict__ VT, unsigned short* __restrict__ Z) {
  __shared__ __align__(16) char lds[65536];

  int tid = threadIdx.x, lane = tid & 63, w = tid >> 6;
  int l31 = lane & 31, hi = lane >> 5;
  int bid = blockIdx.x;
  int xcd = bid & 7, g = bid >> 3;       // per XCD: 48 blocks = 8 qt x 6 heads
  int qt = 7 - g / 6;                    // descending qt (LPT)
  int bh = xcd + (g % 6) * 8;
  int b = bh / NH_, h = bh % NH_;
  int q0 = qt * 256;
  int qrow1 = q0 + w * 32 + l31;
  int qrow2 = qrow1 + 128;

  const unsigned short* Qb = Q + (size_t)(b * T_) * D_ + h * DH_;
  const unsigned short* Kb = Kg + (size_t)(b * T_) * D_ + h * DH_;
  const unsigned short* VTb = VT + (size_t)(b * NH_ + h) * DH_ * T_;

  bf16x8 qf1[4], qf2[4];
#pragma unroll
  for (int s = 0; s < 4; ++s) {
    qf1[s] = *(const bf16x8*)(Qb + (size_t)qrow1 * D_ + s * 16 + hi * 8);
    qf2[s] = *(const bf16x8*)(Qb + (size_t)qrow2 * D_ + s * 16 + hi * 8);
  }

  // staging geometry (per-lane global source pre-swizzled; LDS dest linear)
  int sRow[2], sCol[2];
#pragma unroll
  for (int c = 0; c < 2; ++c) {
    int pos = ((c * 4 + w) * 64 + lane) * 8;
    int row = pos >> 6, colE = pos & 63;
    sRow[c] = row;
    sCol[c] = colE ^ ((row & 7) << 3);
  }

  // K/V fragment offsets within one 8KB buffer
  int koff[2][4];
#pragma unroll
  for (int n = 0; n < 2; ++n)
#pragma unroll
    for (int s = 0; s < 4; ++s) {
      int row = n * 32 + l31;
      koff[n][s] = row * 128 + ((s * 32 + hi * 16) ^ ((row & 7) << 4));
    }

  f32x16 zt1[2] = {}, zt2[2] = {};
  float l1 = 0.f, l2 = 0.f;
  int ntiles = 4 * qt + 4;   // always even
  int h1lim = 4 * qt + 2;    // half1 computes only t < h1lim

#define STAGE(tt)                                                                  \
  do {                                                                             \
    int kv0 = (tt) * 64;                                                           \
    int kb = ((tt) & 3) << 13;                                                     \
    _Pragma("unroll") for (int c = 0; c < 2; ++c) {                                \
      async16(Kb + (size_t)(kv0 + sRow[c]) * D_ + sCol[c],                         \
              lds + kb + (c * 4 + w) * 1024);                                      \
      async16(VTb + (size_t)sRow[c] * T_ + kv0 + sCol[c],                          \
              lds + 32768 + kb + (c * 4 + w) * 1024);                              \
    }                                                                              \
  } while (0)

  // softmax one 32-kv half: a -> pb[2n],pb[2n+1]; accumulates lr
#define SMAX(a, pb, lr, MASKED, kvb_, n_, qrow_)                                   \
  do {                                                                             \
    if (MASKED) {                                                                  \
      _Pragma("unroll") for (int m = 0; m < 4; ++m)                                \
        _Pragma("unroll") for (int c2 = 0; c2 < 4; ++c2) {                         \
          int kv = (kvb_) + (n_) * 32 + m * 8 + hi * 4 + c2;                       \
          if (kv > (qrow_)) (a)[m * 4 + c2] = -1e30f;                              \
        }                                                                          \
    }                                                                              \
    float u[16];                                                                   \
    _Pragma("unroll") for (int r = 0; r < 16; ++r) {                               \
      u[r] = __builtin_amdgcn_exp2f((a)[r]);                                       \
      (lr) += u[r];                                                                \
    }                                                                              \
    _Pragma("unroll") for (int hf = 0; hf < 2; ++hf) {                             \
      unsigned int A0, A1, B0, B1;                                                 \
      asm("v_cvt_pk_bf16_f32 %0, %1, %2" : "=v"(A0) : "v"(u[hf*8+0]), "v"(u[hf*8+1]));\
      asm("v_cvt_pk_bf16_f32 %0, %1, %2" : "=v"(A1) : "v"(u[hf*8+2]), "v"(u[hf*8+3]));\
      asm("v_cvt_pk_bf16_f32 %0, %1, %2" : "=v"(B0) : "v"(u[hf*8+4]), "v"(u[hf*8+5]));\
      asm("v_cvt_pk_bf16_f32 %0, %1, %2" : "=v"(B1) : "v"(u[hf*8+6]), "v"(u[hf*8+7]));\
      asm("v_permlane32_swap_b32 %0, %1" : "+v"(A0), "+v"(B0));                    \
      asm("v_permlane32_swap_b32 %0, %1" : "+v"(A1), "+v"(B1));                    \
      u32x4 pk; pk[0] = A0; pk[1] = A1; pk[2] = B0; pk[3] = B1;                    \
      (pb)[(n_) * 2 + hf] = __builtin_bit_cast(bf16x8, pk);                        \
    }                                                                              \
  } while (0)

  // prologue: stage subtiles 0,1
  STAGE(0);
  STAGE(1);

#pragma unroll 1
  for (int t = 0; t < ntiles; ++t) {
    if ((t & 1) == 0) {
      __syncthreads();           // drains DMAs for t,t+1; closes reads of t+2,t+3 bufs
      if (t + 2 < ntiles) {
        STAGE(t + 2);
        STAGE(t + 3);
      }
    }
    const char* kbase = lds + ((t & 3) << 13);
    const char* vbase = lds + 32768 + ((t & 3) << 13);
    bool hone = (t < h1lim);     // wave-uniform
    int kvb = t * 64;
    bool m1 = (t >= 4 * qt);
    bool m2 = (t >= 4 * qt + 2);

    bf16x8 pb1[4], pb2[4];
#pragma unroll
    for (int n = 0; n < 2; ++n) {
      f32x16 a1 = {}, a2 = {};
      __builtin_amdgcn_s_setprio(1);
#pragma unroll
      for (int s = 0; s < 4; ++s) {
        bf16x8 kf = *(const bf16x8*)(kbase + koff[n][s]);
        a2 = __builtin_amdgcn_mfma_f32_32x32x16_bf16(kf, qf2[s], a2, 0, 0, 0);
        if (hone)
          a1 = __builtin_amdgcn_mfma_f32_32x32x16_bf16(kf, qf1[s], a1, 0, 0, 0);
      }
      __builtin_amdgcn_s_setprio(0);
      SMAX(a2, pb2, l2, m2, kvb, n, qrow2);
      if (hone) SMAX(a1, pb1, l1, m1, kvb, n, qrow1);
    }

    __builtin_amdgcn_s_setprio(1);
#pragma unroll
    for (int dt = 0; dt < 2; ++dt) {
#pragma unroll
      for (int s = 0; s < 4; ++s) {
        bf16x8 vf = *(const bf16x8*)(vbase + koff[dt][s]);
        zt2[dt] = __builtin_amdgcn_mfma_f32_32x32x16_bf16(vf, pb2[s], zt2[dt], 0, 0, 0);
        if (hone)
          zt1[dt] = __builtin_amdgcn_mfma_f32_32x32x16_bf16(vf, pb1[s], zt1[dt], 0, 0, 0);
      }
    }
    __builtin_amdgcn_s_setprio(0);
  }
#undef STAGE
#undef SMAX

  // epilogue: both halves
  l1 += __shfl_xor(l1, 32);
  l2 += __shfl_xor(l2, 32);
  float inv1 = __builtin_amdgcn_rcpf(l1);
  float inv2 = __builtin_amdgcn_rcpf(l2);
  unsigned short* Zrow1 = Z + (size_t)(b * T_ + qrow1) * D_ + h * DH_;
  unsigned short* Zrow2 = Z + (size_t)(b * T_ + qrow2) * D_ + h * DH_;
#pragma unroll
  for (int dt = 0; dt < 2; ++dt)
#pragma unroll
    for (int m = 0; m < 4; ++m) {
      ushort4 o1, o2;
      o1.x = f2bf(zt1[dt][m * 4 + 0] * inv1);
      o1.y = f2bf(zt1[dt][m * 4 + 1] * inv1);
      o1.z = f2bf(zt1[dt][m * 4 + 2] * inv1);
      o1.w = f2bf(zt1[dt][m * 4 + 3] * inv1);
      *(ushort4*)(Zrow1 + dt * 32 + m * 8 + hi * 4) = o1;
      o2.x = f2bf(zt2[dt][m * 4 + 0] * inv2);
      o2.y = f2bf(zt2[dt][m * 4 + 1] * inv2);
      o2.z = f2bf(zt2[dt][m * 4 + 2] * inv2);
      o2.w = f2bf(zt2[dt][m * 4 + 3] * inv2);
      *(ushort4*)(Zrow2 + dt * 32 + m * 8 + hi * 4) = o2;
    }
}

// ---------------------------------------------------------------- launcher
extern "C" void kernel_launch(void* const* d_in, const int* in_sizes, int n_in,
                              void* d_out, int out_size, void* d_ws, size_t ws_size,
                              hipStream_t stream) {
  (void)in_sizes; (void)n_in; (void)out_size; (void)ws_size;
  const float* x  = (const float*)d_in[0];
  const float* wq = (const float*)d_in[1];
  const float* bq = (const float*)d_in[2];
  const float* wk = (const float*)d_in[3];
  const float* bk = (const float*)d_in[4];
  const float* wv = (const float*)d_in[5];
  const float* bv = (const float*)d_in[6];
  const float* wo = (const float*)d_in[7];
  const float* bo = (const float*)d_in[8];

  char* ws = (char*)d_ws;
  const size_t XB = (size_t)M_ * D_ * 2;   // 12.58 MB
  const size_t WB = (size_t)D_ * D_ * 2;   // 1.18 MB
  unsigned short* xb  = (unsigned short*)(ws);
  unsigned short* wqb = (unsigned short*)(ws + XB);
  unsigned short* wkb = (unsigned short*)(ws + XB + WB);
  unsigned short* wvb = (unsigned short*)(ws + XB + 2 * WB);
  unsigned short* wob = (unsigned short*)(ws + XB + 3 * WB);
  unsigned short* Qb  = (unsigned short*)(ws + XB + 4 * WB);
  unsigned short* Kb  = (unsigned short*)(ws + XB + 4 * WB + XB);
  unsigned short* VTb = (unsigned short*)(ws + XB + 4 * WB + 2 * XB);
  unsigned short* Zb  = xb;  // alias: x dead after projections

  const float SCALE_Q = 0.125f * 1.44269504f;  // fold 1/sqrt(64) and log2(e) into Q

  cvt_kernel<<<dim3(1024, 5), 256, 0, stream>>>(x, wq, wk, wv, wo, xb, wqb, wkb, wvb, wob);
  // fused QKV projections (N=2304 as 9 x 256-col tiles); Q prescaled; V writes V^T.
  gemm_kernel<<<dim3(576), 512, 0, stream>>>(
      xb, wqb, wkb, wvb, bq, bk, bv, Qb, Kb, VTb, SCALE_Q, D_, 1);
  // attn: 384 blocks = 48 heads x 8 q-tiles (q=256 each), desc-qt within XCD
  attn_kernel<<<dim3(384), 256, 0, stream>>>(Qb, Kb, VTb, Zb);
  // out projection -> fp32 d_out. grid 192.
  gemm_kernel<<<dim3(192), 512, 0, stream>>>(
      Zb, wob, wob, wob, bo, bo, bo, d_out, d_out, d_out, 1.0f, D_, 0);
}

// Round 16
// 115.365 us; speedup vs baseline: 1.1363x; 1.1363x over previous
//
#include <hip/hip_runtime.h>

// CausalSelfAttention: B=4 T=2048 D=768 NH=12 DH=64, fp32 in/out, bf16 MFMA compute.
// v16: attn reverted to v14 exactly (best: 114.7us). Out-proj moved to a 64x128-tile
// 4-wave variant of the proven v9 pipeline (gemmo_kernel): 768 blocks = exactly
// 3 blocks/CU (was 192 = 75% fill). QKV GEMM + cvt = v9/v14 exact.

#define B_ 4
#define T_ 2048
#define D_ 768
#define NH_ 12
#define DH_ 64
#define M_ (B_ * T_)  // 8192

typedef __attribute__((ext_vector_type(8))) short bf16x8;    // 8 bf16 = 4 VGPRs
typedef __attribute__((ext_vector_type(4))) float f32x4;
typedef __attribute__((ext_vector_type(16))) float f32x16;
typedef __attribute__((ext_vector_type(4))) unsigned int u32x4;

__device__ __forceinline__ unsigned short f2bf(float f) {
  unsigned int u = __builtin_bit_cast(unsigned int, f);
  u += 0x7FFFu + ((u >> 16) & 1u);  // RNE
  return (unsigned short)(u >> 16);
}

__device__ __forceinline__ void async16(const void* g, void* l) {
  // global->LDS DMA, 16B/lane; LDS dest = wave-uniform base + lane*16 (m97/m104)
  __builtin_amdgcn_global_load_lds(
      (const __attribute__((address_space(1))) unsigned int*)g,
      (__attribute__((address_space(3))) unsigned int*)l, 16, 0, 0);
}

// raw barrier with compiler-level memory fence (no vmcnt drain, unlike __syncthreads)
#define RAW_BARRIER()                         \
  do {                                        \
    asm volatile("" ::: "memory");            \
    __builtin_amdgcn_s_barrier();             \
    asm volatile("" ::: "memory");            \
  } while (0)

// ---------------------------------------------------------------- cvt fp32->bf16
__global__ void cvt_kernel(const float* __restrict__ x, const float* __restrict__ wq,
                           const float* __restrict__ wk, const float* __restrict__ wv,
                           const float* __restrict__ wo,
                           unsigned short* __restrict__ xb, unsigned short* __restrict__ wqb,
                           unsigned short* __restrict__ wkb, unsigned short* __restrict__ wvb,
                           unsigned short* __restrict__ wob) {
  const float* src; unsigned short* dst; int n4;
  switch (blockIdx.y) {
    case 0: src = x;  dst = xb;  n4 = M_ * D_ / 4; break;
    case 1: src = wq; dst = wqb; n4 = D_ * D_ / 4; break;
    case 2: src = wk; dst = wkb; n4 = D_ * D_ / 4; break;
    case 3: src = wv; dst = wvb; n4 = D_ * D_ / 4; break;
    default: src = wo; dst = wob; n4 = D_ * D_ / 4; break;
  }
  int stride = gridDim.x * blockDim.x;
  for (int i = blockIdx.x * blockDim.x + threadIdx.x; i < n4; i += stride) {
    float4 v = ((const float4*)src)[i];
    ushort4 o;
    o.x = f2bf(v.x); o.y = f2bf(v.y); o.z = f2bf(v.z); o.w = f2bf(v.w);
    ((ushort4*)dst)[i] = o;
  }
}

// ---------------------------------------------------------------- bf16 GEMM (QKV)
// v9 exact: 128x256 tile, BK=32, 8 waves; 3 LDS slots x 24KB; depth-2 counted-vmcnt.
// grid 576 = 8 xcd x (8 mg x 9 nt); nt 0-2 Q, 3-5 K, 6-8 V(V^T out).
__global__ __launch_bounds__(512, 4) void gemm_kernel(
    const unsigned short* __restrict__ A,
    const unsigned short* __restrict__ W0, const unsigned short* __restrict__ W1,
    const unsigned short* __restrict__ W2,
    const float* __restrict__ bias0, const float* __restrict__ bias1,
    const float* __restrict__ bias2,
    void* out0, void* out1, void* out2,
    float s0, int K) {
  __shared__ __align__(16) char lds[73728];   // 3 slots x 24576 (A@0, B@8192)

  int bid = blockIdx.x;
  int xcd = bid & 7, g = bid >> 3;
  int mt = xcd + (g / 9) * 8, nt = g % 9;
  int y  = nt / 3;
  int nW = nt % 3;                        // 256-col tile within the 768-wide region
  const unsigned short* W = y == 0 ? W0 : (y == 1 ? W1 : W2);
  const float* bias = y == 0 ? bias0 : (y == 1 ? bias1 : bias2);
  void* outp = y == 0 ? out0 : (y == 1 ? out1 : out2);
  float scl = (y == 0) ? s0 : 1.0f;
  int mode = (y == 2) ? 2 : 1;

  int tid = threadIdx.x, lane = tid & 63, wid = tid >> 6;
  int l15 = lane & 15, l4 = lane >> 4;
  int wm = wid >> 2, wn = wid & 3;
  int m0 = mt << 7, n0w = nW << 8;       // n0w in [0,768)

  int aRow, aCol;
  {
    int row = wid * 16 + (lane >> 2);
    int colE = (lane & 3) * 8;
    aRow = row;
    aCol = colE ^ (((row >> 1) & 3) << 3);
  }
  int bRow[2], bCol[2];
#pragma unroll
  for (int c = 0; c < 2; ++c) {
    int u = c * 8 + wid;
    int row = u * 16 + (lane >> 2);
    int colE = (lane & 3) * 8;
    bRow[c] = row;
    bCol[c] = colE ^ (((row >> 1) & 3) << 3);
  }

  int aoff[4], boff[4];
#pragma unroll
  for (int mf = 0; mf < 4; ++mf) {
    int row = wm * 64 + mf * 16 + l15;
    aoff[mf] = row * 64 + ((l4 * 16) ^ (((row >> 1) & 3) << 4));
  }
#pragma unroll
  for (int nf = 0; nf < 4; ++nf) {
    int row = wn * 64 + nf * 16 + l15;
    boff[nf] = 8192 + row * 64 + ((l4 * 16) ^ (((row >> 1) & 3) << 4));
  }

  const unsigned short* Wb = W + (size_t)n0w * K;   // 256-row W panel

#define ISSUE_TILE(kt, slot)                                                       \
  do {                                                                             \
    async16(A + (size_t)(m0 + aRow) * K + (kt) + aCol, (slot) + wid * 1024);       \
    _Pragma("unroll") for (int c = 0; c < 2; ++c)                                  \
      async16(Wb + (size_t)bRow[c] * K + (kt) + bCol[c],                           \
              (slot) + 8192 + (c * 8 + wid) * 1024);                               \
  } while (0)

  f32x4 acc[4][4] = {};
  char* b0 = lds;             // compute slot (tile t)
  char* b1 = lds + 24576;     // tile t+1 (in flight)
  char* b2 = lds + 49152;     // issue target (tile t+2)

  ISSUE_TILE(0, b0);
  ISSUE_TILE(32, b1);

  int NT = K >> 5;   // 24
#pragma unroll 1
  for (int t = 0; t < NT; ++t) {
    if (t + 1 < NT) asm volatile("s_waitcnt vmcnt(3)" ::: "memory");  // tile t landed
    else            asm volatile("s_waitcnt vmcnt(0)" ::: "memory");  // tail drain
    RAW_BARRIER();   // all waves: tile t visible; slot b2 (tile t-1) free
    if (t + 2 < NT) ISSUE_TILE((t + 2) << 5, b2);
    bf16x8 af[4], bfr[4];
#pragma unroll
    for (int mf = 0; mf < 4; ++mf) af[mf] = *(const bf16x8*)(b0 + aoff[mf]);
#pragma unroll
    for (int nf = 0; nf < 4; ++nf) bfr[nf] = *(const bf16x8*)(b0 + boff[nf]);
    __builtin_amdgcn_s_setprio(1);
#pragma unroll
    for (int mf = 0; mf < 4; ++mf)
#pragma unroll
      for (int nf = 0; nf < 4; ++nf)
        acc[mf][nf] = __builtin_amdgcn_mfma_f32_16x16x32_bf16(af[mf], bfr[nf], acc[mf][nf], 0, 0, 0);
    __builtin_amdgcn_s_setprio(0);
    char* tmp = b0; b0 = b1; b1 = b2; b2 = tmp;   // rotate slots
  }
#undef ISSUE_TILE

  // epilogue
  if (mode == 2) {
#pragma unroll
    for (int nf = 0; nf < 4; ++nf) {
      int colW = n0w + wn * 64 + nf * 16 + l15;   // = h*DH + d
      float bv = bias[colW];
      int h = colW >> 6, d = colW & 63;
#pragma unroll
      for (int mf = 0; mf < 4; ++mf) {
        int rbase = m0 + wm * 64 + mf * 16 + l4 * 4;   // = b*T + t
        int bb = rbase >> 11, tt = rbase & (T_ - 1);
        ushort4 o;
        o.x = f2bf(acc[mf][nf][0] + bv);
        o.y = f2bf(acc[mf][nf][1] + bv);
        o.z = f2bf(acc[mf][nf][2] + bv);
        o.w = f2bf(acc[mf][nf][3] + bv);
        *(ushort4*)((unsigned short*)outp + ((size_t)(bb * NH_ + h) * DH_ + d) * T_ + tt) = o;
      }
    }
  } else {
#pragma unroll
    for (int nf = 0; nf < 4; ++nf) {
      int colW = n0w + wn * 64 + nf * 16 + l15;
      float bv = bias[colW];
#pragma unroll
      for (int mf = 0; mf < 4; ++mf) {
        int rbase = m0 + wm * 64 + mf * 16 + l4 * 4;
#pragma unroll
        for (int r = 0; r < 4; ++r) {
          float v = (acc[mf][nf][r] + bv) * scl;
          size_t idx = (size_t)(rbase + r) * D_ + colW;
          ((unsigned short*)outp)[idx] = f2bf(v);
        }
      }
    }
  }
}

// ---------------------------------------------------------------- out-proj GEMM
// 64x128 tile, 4 waves (wm=wid>>1: 32-row half, wn=wid&1: 64-col half; per-wave
// 32x64 out, acc[2][4]). Same v9 pipeline skeleton: 3 LDS slots x 12KB (A 4KB@0,
// B 8KB@4096), depth-2 counted vmcnt(3) (3 DMAs/thread/tile), same 64B-row swizzle.
// grid 768 = 8 xcd x (16 mg x 6 nt) -> exactly 3 blocks/CU. fp32 out.
__global__ __launch_bounds__(256) void gemmo_kernel(
    const unsigned short* __restrict__ A,
    const unsigned short* __restrict__ W0,
    const float* __restrict__ bias0,
    float* __restrict__ out0, int K) {
  __shared__ __align__(16) char lds[36864];   // 3 slots x 12288

  int bid = blockIdx.x;
  int xcd = bid & 7, g = bid >> 3;
  int mt = xcd + (g / 6) * 8;             // 0..127
  int nW = g % 6;                         // 0..5 (128-col tiles)

  int tid = threadIdx.x, lane = tid & 63, wid = tid >> 6;  // 4 waves
  int l15 = lane & 15, l4 = lane >> 4;
  int wm = wid >> 1, wn = wid & 1;
  int m0 = mt << 6, n0w = nW << 7;        // 64-row, 128-col tile

  // A staging: 64x32 elem = 4KB = 4 chunks of 1KB; wave wid stages chunk wid
  int aRow, aCol;
  {
    int row = wid * 16 + (lane >> 2);
    int colE = (lane & 3) * 8;
    aRow = row;
    aCol = colE ^ (((row >> 1) & 3) << 3);
  }
  // B staging: 128x32 elem = 8KB = 8 chunks; wave stages {wid, wid+4}
  int bRow[2], bCol[2];
#pragma unroll
  for (int c = 0; c < 2; ++c) {
    int row = (c * 4 + wid) * 16 + (lane >> 2);
    bRow[c] = row;
    bCol[c] = ((lane & 3) * 8) ^ (((row >> 1) & 3) << 3);
  }

  int aoff[2], boff[4];
#pragma unroll
  for (int mf = 0; mf < 2; ++mf) {
    int row = wm * 32 + mf * 16 + l15;
    aoff[mf] = row * 64 + ((l4 * 16) ^ (((row >> 1) & 3) << 4));
  }
#pragma unroll
  for (int nf = 0; nf < 4; ++nf) {
    int row = wn * 64 + nf * 16 + l15;
    boff[nf] = 4096 + row * 64 + ((l4 * 16) ^ (((row >> 1) & 3) << 4));
  }

  const unsigned short* Wb = W0 + (size_t)n0w * K;  // 128-row W panel

#define ISSUE_O(kt, slot)                                                          \
  do {                                                                             \
    async16(A + (size_t)(m0 + aRow) * K + (kt) + aCol, (slot) + wid * 1024);       \
    _Pragma("unroll") for (int c = 0; c < 2; ++c)                                  \
      async16(Wb + (size_t)bRow[c] * K + (kt) + bCol[c],                           \
              (slot) + 4096 + (c * 4 + wid) * 1024);                               \
  } while (0)

  f32x4 acc[2][4] = {};
  char* b0 = lds;
  char* b1 = lds + 12288;
  char* b2 = lds + 24576;

  ISSUE_O(0, b0);
  ISSUE_O(32, b1);

  int NT = K >> 5;   // 24
#pragma unroll 1
  for (int t = 0; t < NT; ++t) {
    if (t + 1 < NT) asm volatile("s_waitcnt vmcnt(3)" ::: "memory");
    else            asm volatile("s_waitcnt vmcnt(0)" ::: "memory");
    RAW_BARRIER();
    if (t + 2 < NT) ISSUE_O((t + 2) << 5, b2);
    bf16x8 af[2], bfr[4];
#pragma unroll
    for (int mf = 0; mf < 2; ++mf) af[mf] = *(const bf16x8*)(b0 + aoff[mf]);
#pragma unroll
    for (int nf = 0; nf < 4; ++nf) bfr[nf] = *(const bf16x8*)(b0 + boff[nf]);
    __builtin_amdgcn_s_setprio(1);
#pragma unroll
    for (int mf = 0; mf < 2; ++mf)
#pragma unroll
      for (int nf = 0; nf < 4; ++nf)
        acc[mf][nf] = __builtin_amdgcn_mfma_f32_16x16x32_bf16(af[mf], bfr[nf], acc[mf][nf], 0, 0, 0);
    __builtin_amdgcn_s_setprio(0);
    char* tmp = b0; b0 = b1; b1 = b2; b2 = tmp;
  }
#undef ISSUE_O

#pragma unroll
  for (int nf = 0; nf < 4; ++nf) {
    int colW = n0w + wn * 64 + nf * 16 + l15;
    float bv = bias0[colW];
#pragma unroll
    for (int mf = 0; mf < 2; ++mf) {
      int rbase = m0 + wm * 32 + mf * 16 + l4 * 4;
#pragma unroll
      for (int r = 0; r < 4; ++r)
        out0[(size_t)(rbase + r) * D_ + colW] = acc[mf][nf][r] + bv;
    }
  }
}

// ---------------------------------------------------------------- flash attention v14
// Block = q-tile of 128 rows; 4 waves x 32 q-rows; 32x32x16 MFMA; swapped QK^T;
// raw-exp2 softmax; P in registers (cvt_pk + permlane32_swap). Paired-KV staging:
// 4 K + 4 V bufs (64KB), {__syncthreads; stage t+2,t+3} at even t. Desc-qt LPT grid.
__global__ __launch_bounds__(256, 2) void attn_kernel(
    const unsigned short* __restrict__ Q, const unsigned short* __restrict__ Kg,
    const unsigned short* __restrict__ VT, unsigned short* __restrict__ Z) {
  __shared__ __align__(16) char lds[65536];

  int tid = threadIdx.x, lane = tid & 63, w = tid >> 6;
  int l31 = lane & 31, hi = lane >> 5;
  int bid = blockIdx.x;
  int xcd = bid & 7, g = bid >> 3;       // per XCD: 96 blocks = 16 qt x 6 heads
  int qt = 15 - g / 6;                   // descending qt: big blocks dispatch first (LPT)
  int bh = xcd + (g % 6) * 8;
  int b = bh / NH_, h = bh % NH_;
  int q0 = qt * 128;
  int qrow = q0 + w * 32 + l31;

  const unsigned short* Qb = Q + (size_t)(b * T_) * D_ + h * DH_;
  const unsigned short* Kb = Kg + (size_t)(b * T_) * D_ + h * DH_;
  const unsigned short* VTb = VT + (size_t)(b * NH_ + h) * DH_ * T_;

  bf16x8 qf[4];
#pragma unroll
  for (int s = 0; s < 4; ++s)
    qf[s] = *(const bf16x8*)(Qb + (size_t)qrow * D_ + s * 16 + hi * 8);

  int sRow[2], sCol[2];
#pragma unroll
  for (int c = 0; c < 2; ++c) {
    int pos = ((c * 4 + w) * 64 + lane) * 8;
    int row = pos >> 6, colE = pos & 63;
    sRow[c] = row;
    sCol[c] = colE ^ ((row & 7) << 3);
  }

  int koff[2][4];
#pragma unroll
  for (int n = 0; n < 2; ++n)
#pragma unroll
    for (int s = 0; s < 4; ++s) {
      int row = n * 32 + l31;
      koff[n][s] = row * 128 + ((s * 32 + hi * 16) ^ ((row & 7) << 4));
    }

  f32x16 zt[2] = {};
  float l_run = 0.f;
  int ntiles = 2 * qt + 2;   // always even

#define STAGE(tt)                                                                  \
  do {                                                                             \
    int kv0 = (tt) * 64;                                                           \
    int kb = ((tt) & 3) << 13;                                                     \
    _Pragma("unroll") for (int c = 0; c < 2; ++c) {                                \
      async16(Kb + (size_t)(kv0 + sRow[c]) * D_ + sCol[c],                         \
              lds + kb + (c * 4 + w) * 1024);                                      \
      async16(VTb + (size_t)sRow[c] * T_ + kv0 + sCol[c],                          \
              lds + 32768 + kb + (c * 4 + w) * 1024);                              \
    }                                                                              \
  } while (0)

  STAGE(0);
  STAGE(1);

#pragma unroll 1
  for (int t = 0; t < ntiles; ++t) {
    if ((t & 1) == 0) {
      __syncthreads();           // drains DMAs for t,t+1; closes reads of t+2,t+3 bufs
      if (t + 2 < ntiles) {
        STAGE(t + 2);
        STAGE(t + 3);
      }
    }
    const char* kbase = lds + ((t & 3) << 13);
    const char* vbase = lds + 32768 + ((t & 3) << 13);

    f32x16 st[2];
    __builtin_amdgcn_s_setprio(1);
#pragma unroll
    for (int n = 0; n < 2; ++n) {
      f32x16 a = {};
#pragma unroll
      for (int s = 0; s < 4; ++s) {
        bf16x8 kf = *(const bf16x8*)(kbase + koff[n][s]);
        a = __builtin_amdgcn_mfma_f32_32x32x16_bf16(kf, qf[s], a, 0, 0, 0);
      }
      st[n] = a;
    }
    __builtin_amdgcn_s_setprio(0);

    if (t >= 2 * qt) {  // diagonal 128-pair: mask kv > qrow
      int kvb = t * 64;
#pragma unroll
      for (int n = 0; n < 2; ++n)
#pragma unroll
        for (int m = 0; m < 4; ++m)
#pragma unroll
          for (int c2 = 0; c2 < 4; ++c2) {
            int kv = kvb + n * 32 + m * 8 + hi * 4 + c2;
            if (kv > qrow) st[n][m * 4 + c2] = -1e30f;
          }
    }

    bf16x8 pb[4];
#pragma unroll
    for (int n = 0; n < 2; ++n) {
      float u[16];
#pragma unroll
      for (int r = 0; r < 16; ++r) {
        u[r] = __builtin_amdgcn_exp2f(st[n][r]);
        l_run += u[r];
      }
#pragma unroll
      for (int hf = 0; hf < 2; ++hf) {
        unsigned int A0, A1, B0, B1;
        asm("v_cvt_pk_bf16_f32 %0, %1, %2" : "=v"(A0) : "v"(u[hf*8+0]), "v"(u[hf*8+1]));
        asm("v_cvt_pk_bf16_f32 %0, %1, %2" : "=v"(A1) : "v"(u[hf*8+2]), "v"(u[hf*8+3]));
        asm("v_cvt_pk_bf16_f32 %0, %1, %2" : "=v"(B0) : "v"(u[hf*8+4]), "v"(u[hf*8+5]));
        asm("v_cvt_pk_bf16_f32 %0, %1, %2" : "=v"(B1) : "v"(u[hf*8+6]), "v"(u[hf*8+7]));
        asm("v_permlane32_swap_b32 %0, %1" : "+v"(A0), "+v"(B0));
        asm("v_permlane32_swap_b32 %0, %1" : "+v"(A1), "+v"(B1));
        u32x4 pk; pk[0] = A0; pk[1] = A1; pk[2] = B0; pk[3] = B1;
        pb[n * 2 + hf] = __builtin_bit_cast(bf16x8, pk);
      }
    }

    __builtin_amdgcn_s_setprio(1);
#pragma unroll
    for (int dt = 0; dt < 2; ++dt) {
#pragma unroll
      for (int s = 0; s < 4; ++s) {
        bf16x8 vf = *(const bf16x8*)(vbase + koff[dt][s]);
        zt[dt] = __builtin_amdgcn_mfma_f32_32x32x16_bf16(vf, pb[s], zt[dt], 0, 0, 0);
      }
    }
    __builtin_amdgcn_s_setprio(0);
  }
#undef STAGE

  l_run += __shfl_xor(l_run, 32);
  float inv = __builtin_amdgcn_rcpf(l_run);
  unsigned short* Zrow = Z + (size_t)(b * T_ + qrow) * D_ + h * DH_;
#pragma unroll
  for (int dt = 0; dt < 2; ++dt)
#pragma unroll
    for (int m = 0; m < 4; ++m) {
      ushort4 o;
      o.x = f2bf(zt[dt][m * 4 + 0] * inv);
      o.y = f2bf(zt[dt][m * 4 + 1] * inv);
      o.z = f2bf(zt[dt][m * 4 + 2] * inv);
      o.w = f2bf(zt[dt][m * 4 + 3] * inv);
      *(ushort4*)(Zrow + dt * 32 + m * 8 + hi * 4) = o;  // d = 32dt + 8m + 4hi + c
    }
}

// ---------------------------------------------------------------- launcher
extern "C" void kernel_launch(void* const* d_in, const int* in_sizes, int n_in,
                              void* d_out, int out_size, void* d_ws, size_t ws_size,
                              hipStream_t stream) {
  (void)in_sizes; (void)n_in; (void)out_size; (void)ws_size;
  const float* x  = (const float*)d_in[0];
  const float* wq = (const float*)d_in[1];
  const float* bq = (const float*)d_in[2];
  const float* wk = (const float*)d_in[3];
  const float* bk = (const float*)d_in[4];
  const float* wv = (const float*)d_in[5];
  const float* bv = (const float*)d_in[6];
  const float* wo = (const float*)d_in[7];
  const float* bo = (const float*)d_in[8];

  char* ws = (char*)d_ws;
  const size_t XB = (size_t)M_ * D_ * 2;   // 12.58 MB
  const size_t WB = (size_t)D_ * D_ * 2;   // 1.18 MB
  unsigned short* xb  = (unsigned short*)(ws);
  unsigned short* wqb = (unsigned short*)(ws + XB);
  unsigned short* wkb = (unsigned short*)(ws + XB + WB);
  unsigned short* wvb = (unsigned short*)(ws + XB + 2 * WB);
  unsigned short* wob = (unsigned short*)(ws + XB + 3 * WB);
  unsigned short* Qb  = (unsigned short*)(ws + XB + 4 * WB);
  unsigned short* Kb  = (unsigned short*)(ws + XB + 4 * WB + XB);
  unsigned short* VTb = (unsigned short*)(ws + XB + 4 * WB + 2 * XB);
  unsigned short* Zb  = xb;  // alias: x dead after projections

  const float SCALE_Q = 0.125f * 1.44269504f;  // fold 1/sqrt(64) and log2(e) into Q

  cvt_kernel<<<dim3(1024, 5), 256, 0, stream>>>(x, wq, wk, wv, wo, xb, wqb, wkb, wvb, wob);
  // fused QKV projections (N=2304 as 9 x 256-col tiles); Q prescaled; V writes V^T.
  gemm_kernel<<<dim3(576), 512, 0, stream>>>(
      xb, wqb, wkb, wvb, bq, bk, bv, Qb, Kb, VTb, SCALE_Q, D_);
  // attn: 768 blocks = 48 heads x 16 q-tiles (q=128 each), desc-qt within XCD
  attn_kernel<<<dim3(768), 256, 0, stream>>>(Qb, Kb, VTb, Zb);
  // out projection -> fp32 d_out. 768 blocks = 3/CU exact fill.
  gemmo_kernel<<<dim3(768), 256, 0, stream>>>(Zb, wob, bo, (float*)d_out, D_);
}

// Round 17
// 115.223 us; speedup vs baseline: 1.1377x; 1.0012x over previous
//
#include <hip/hip_runtime.h>

// CausalSelfAttention: B=4 T=2048 D=768 NH=12 DH=64, fp32 in/out, bf16 MFMA compute.
// FINAL (v14 exact, best measured: 114.7us):
//  - cvt: fp32->bf16 vectorized pass (x + 4 weights).
//  - QKV GEMM: fused N=2304, 128x256 tile, BK=32, 8 waves, 3 LDS slots (72KB),
//    depth-2 counted-vmcnt pipeline {vmcnt(3); barrier; issue t+2; compute t},
//    64B-row involution swizzle via pre-swizzled global source (0 conflicts),
//    Q prescaled by 0.125*log2e, V written transposed [(b,h,d)][t].
//  - attn: flash, q=128/block, 4 waves x 32 q-rows, 32x32x16 MFMA, swapped QK^T
//    (kv lane-local), raw-exp2 softmax (no max tracking), P entirely in registers
//    via v_cvt_pk_bf16_f32 + v_permlane32_swap_b32; paired-KV staging (4K+4V bufs,
//    64KB, one __syncthreads per 2 subtiles); desc-qt LPT grid, XCD-aware decode.
//  - out-proj: same GEMM kernel, fp32 epilogue.

#define B_ 4
#define T_ 2048
#define D_ 768
#define NH_ 12
#define DH_ 64
#define M_ (B_ * T_)  // 8192

typedef __attribute__((ext_vector_type(8))) short bf16x8;    // 8 bf16 = 4 VGPRs
typedef __attribute__((ext_vector_type(4))) float f32x4;
typedef __attribute__((ext_vector_type(16))) float f32x16;
typedef __attribute__((ext_vector_type(4))) unsigned int u32x4;

__device__ __forceinline__ unsigned short f2bf(float f) {
  unsigned int u = __builtin_bit_cast(unsigned int, f);
  u += 0x7FFFu + ((u >> 16) & 1u);  // RNE
  return (unsigned short)(u >> 16);
}

__device__ __forceinline__ void async16(const void* g, void* l) {
  // global->LDS DMA, 16B/lane; LDS dest = wave-uniform base + lane*16 (m97/m104)
  __builtin_amdgcn_global_load_lds(
      (const __attribute__((address_space(1))) unsigned int*)g,
      (__attribute__((address_space(3))) unsigned int*)l, 16, 0, 0);
}

// raw barrier with compiler-level memory fence (no vmcnt drain, unlike __syncthreads)
#define RAW_BARRIER()                         \
  do {                                        \
    asm volatile("" ::: "memory");            \
    __builtin_amdgcn_s_barrier();             \
    asm volatile("" ::: "memory");            \
  } while (0)

// ---------------------------------------------------------------- cvt fp32->bf16
__global__ void cvt_kernel(const float* __restrict__ x, const float* __restrict__ wq,
                           const float* __restrict__ wk, const float* __restrict__ wv,
                           const float* __restrict__ wo,
                           unsigned short* __restrict__ xb, unsigned short* __restrict__ wqb,
                           unsigned short* __restrict__ wkb, unsigned short* __restrict__ wvb,
                           unsigned short* __restrict__ wob) {
  const float* src; unsigned short* dst; int n4;
  switch (blockIdx.y) {
    case 0: src = x;  dst = xb;  n4 = M_ * D_ / 4; break;
    case 1: src = wq; dst = wqb; n4 = D_ * D_ / 4; break;
    case 2: src = wk; dst = wkb; n4 = D_ * D_ / 4; break;
    case 3: src = wv; dst = wvb; n4 = D_ * D_ / 4; break;
    default: src = wo; dst = wob; n4 = D_ * D_ / 4; break;
  }
  int stride = gridDim.x * blockDim.x;
  for (int i = blockIdx.x * blockDim.x + threadIdx.x; i < n4; i += stride) {
    float4 v = ((const float4*)src)[i];
    ushort4 o;
    o.x = f2bf(v.x); o.y = f2bf(v.y); o.z = f2bf(v.z); o.w = f2bf(v.w);
    ((ushort4*)dst)[i] = o;
  }
}

// ---------------------------------------------------------------- bf16 GEMM (B^T input)
// 128x256 tile, BK=32, 8 waves (wm=wid>>2, wn=wid&3; per-wave 64x64 out).
// 3 LDS slots x 24KB = 72KB; depth-2 pipeline, 1 barrier + vmcnt(3)/iter. 64B LDS
// rows, involution swizzle byte^=((row>>1)&3)<<4 via pre-swizzled global source.
// qkv=1: grid 576 = 8 xcd x (8 mg x 9 nt); nt 0-2 Q, 3-5 K, 6-8 V(V^T out).
// qkv=0: grid 192, fp32 out.
__global__ __launch_bounds__(512, 4) void gemm_kernel(
    const unsigned short* __restrict__ A,
    const unsigned short* __restrict__ W0, const unsigned short* __restrict__ W1,
    const unsigned short* __restrict__ W2,
    const float* __restrict__ bias0, const float* __restrict__ bias1,
    const float* __restrict__ bias2,
    void* out0, void* out1, void* out2,
    float s0, int K, int qkv) {
  __shared__ __align__(16) char lds[73728];   // 3 slots x 24576 (A@0, B@8192)

  int bid = blockIdx.x;
  int xcd = bid & 7, g = bid >> 3;
  int mt, nt;
  if (qkv) { mt = xcd + (g / 9) * 8; nt = g % 9; }
  else     { mt = xcd + (g / 3) * 8;  nt = g % 3; }
  int y  = qkv ? nt / 3 : 0;
  int nW = qkv ? nt % 3 : nt;            // 256-col tile within the 768-wide region
  const unsigned short* W = y == 0 ? W0 : (y == 1 ? W1 : W2);
  const float* bias = y == 0 ? bias0 : (y == 1 ? bias1 : bias2);
  void* outp = y == 0 ? out0 : (y == 1 ? out1 : out2);
  float scl = (qkv && y == 0) ? s0 : 1.0f;
  int mode = qkv ? ((y == 2) ? 2 : 1) : 0;

  int tid = threadIdx.x, lane = tid & 63, wid = tid >> 6;
  int l15 = lane & 15, l4 = lane >> 4;
  int wm = wid >> 2, wn = wid & 3;
  int m0 = mt << 7, n0w = nW << 8;       // n0w in [0,768)

  // A: 8KB = 8 chunks of 1KB; wave wid owns chunk wid
  int aRow, aCol;
  {
    int row = wid * 16 + (lane >> 2);
    int colE = (lane & 3) * 8;
    aRow = row;
    aCol = colE ^ (((row >> 1) & 3) << 3);
  }
  // B: 16KB = 16 chunks of 1KB; wave owns {wid, wid+8}
  int bRow[2], bCol[2];
#pragma unroll
  for (int c = 0; c < 2; ++c) {
    int u = c * 8 + wid;
    int row = u * 16 + (lane >> 2);
    int colE = (lane & 3) * 8;
    bRow[c] = row;
    bCol[c] = colE ^ (((row >> 1) & 3) << 3);
  }

  int aoff[4], boff[4];
#pragma unroll
  for (int mf = 0; mf < 4; ++mf) {
    int row = wm * 64 + mf * 16 + l15;
    aoff[mf] = row * 64 + ((l4 * 16) ^ (((row >> 1) & 3) << 4));
  }
#pragma unroll
  for (int nf = 0; nf < 4; ++nf) {
    int row = wn * 64 + nf * 16 + l15;
    boff[nf] = 8192 + row * 64 + ((l4 * 16) ^ (((row >> 1) & 3) << 4));
  }

  const unsigned short* Wb = W + (size_t)n0w * K;   // 256-row W panel

#define ISSUE_TILE(kt, slot)                                                       \
  do {                                                                             \
    async16(A + (size_t)(m0 + aRow) * K + (kt) + aCol, (slot) + wid * 1024);       \
    _Pragma("unroll") for (int c = 0; c < 2; ++c)                                  \
      async16(Wb + (size_t)bRow[c] * K + (kt) + bCol[c],                           \
              (slot) + 8192 + (c * 8 + wid) * 1024);                               \
  } while (0)

  f32x4 acc[4][4] = {};
  char* b0 = lds;             // compute slot (tile t)
  char* b1 = lds + 24576;     // tile t+1 (in flight)
  char* b2 = lds + 49152;     // issue target (tile t+2)

  ISSUE_TILE(0, b0);
  ISSUE_TILE(32, b1);

  int NT = K >> 5;   // 24
#pragma unroll 1
  for (int t = 0; t < NT; ++t) {
    if (t + 1 < NT) asm volatile("s_waitcnt vmcnt(3)" ::: "memory");  // tile t landed
    else            asm volatile("s_waitcnt vmcnt(0)" ::: "memory");  // tail drain
    RAW_BARRIER();   // all waves: tile t visible; slot b2 (tile t-1) free
    if (t + 2 < NT) ISSUE_TILE((t + 2) << 5, b2);
    bf16x8 af[4], bfr[4];
#pragma unroll
    for (int mf = 0; mf < 4; ++mf) af[mf] = *(const bf16x8*)(b0 + aoff[mf]);
#pragma unroll
    for (int nf = 0; nf < 4; ++nf) bfr[nf] = *(const bf16x8*)(b0 + boff[nf]);
    __builtin_amdgcn_s_setprio(1);
#pragma unroll
    for (int mf = 0; mf < 4; ++mf)
#pragma unroll
      for (int nf = 0; nf < 4; ++nf)
        acc[mf][nf] = __builtin_amdgcn_mfma_f32_16x16x32_bf16(af[mf], bfr[nf], acc[mf][nf], 0, 0, 0);
    __builtin_amdgcn_s_setprio(0);
    char* tmp = b0; b0 = b1; b1 = b2; b2 = tmp;   // rotate slots
  }
#undef ISSUE_TILE

  // epilogue
  if (mode == 2) {
#pragma unroll
    for (int nf = 0; nf < 4; ++nf) {
      int colW = n0w + wn * 64 + nf * 16 + l15;   // = h*DH + d
      float bv = bias[colW];
      int h = colW >> 6, d = colW & 63;
#pragma unroll
      for (int mf = 0; mf < 4; ++mf) {
        int rbase = m0 + wm * 64 + mf * 16 + l4 * 4;   // = b*T + t
        int bb = rbase >> 11, tt = rbase & (T_ - 1);
        ushort4 o;
        o.x = f2bf(acc[mf][nf][0] + bv);
        o.y = f2bf(acc[mf][nf][1] + bv);
        o.z = f2bf(acc[mf][nf][2] + bv);
        o.w = f2bf(acc[mf][nf][3] + bv);
        *(ushort4*)((unsigned short*)outp + ((size_t)(bb * NH_ + h) * DH_ + d) * T_ + tt) = o;
      }
    }
  } else {
#pragma unroll
    for (int nf = 0; nf < 4; ++nf) {
      int colW = n0w + wn * 64 + nf * 16 + l15;
      float bv = bias[colW];
#pragma unroll
      for (int mf = 0; mf < 4; ++mf) {
        int rbase = m0 + wm * 64 + mf * 16 + l4 * 4;
#pragma unroll
        for (int r = 0; r < 4; ++r) {
          float v = (acc[mf][nf][r] + bv) * scl;
          size_t idx = (size_t)(rbase + r) * D_ + colW;
          if (mode == 1) ((unsigned short*)outp)[idx] = f2bf(v);
          else           ((float*)outp)[idx] = v;
        }
      }
    }
  }
}

// ---------------------------------------------------------------- flash attention v14
// Block = q-tile of 128 rows; 4 waves x 32 q-rows; 32x32x16 MFMA; swapped QK^T;
// raw-exp2 softmax; P in registers (cvt_pk + permlane32_swap). Paired-KV staging:
// 4 K + 4 V bufs (64KB), {__syncthreads; stage t+2,t+3} at even t. Desc-qt LPT grid.
__global__ __launch_bounds__(256, 2) void attn_kernel(
    const unsigned short* __restrict__ Q, const unsigned short* __restrict__ Kg,
    const unsigned short* __restrict__ VT, unsigned short* __restrict__ Z) {
  __shared__ __align__(16) char lds[65536];

  int tid = threadIdx.x, lane = tid & 63, w = tid >> 6;
  int l31 = lane & 31, hi = lane >> 5;
  int bid = blockIdx.x;
  int xcd = bid & 7, g = bid >> 3;       // per XCD: 96 blocks = 16 qt x 6 heads
  int qt = 15 - g / 6;                   // descending qt: big blocks dispatch first (LPT)
  int bh = xcd + (g % 6) * 8;
  int b = bh / NH_, h = bh % NH_;
  int q0 = qt * 128;
  int qrow = q0 + w * 32 + l31;

  const unsigned short* Qb = Q + (size_t)(b * T_) * D_ + h * DH_;
  const unsigned short* Kb = Kg + (size_t)(b * T_) * D_ + h * DH_;
  const unsigned short* VTb = VT + (size_t)(b * NH_ + h) * DH_ * T_;

  bf16x8 qf[4];
#pragma unroll
  for (int s = 0; s < 4; ++s)
    qf[s] = *(const bf16x8*)(Qb + (size_t)qrow * D_ + s * 16 + hi * 8);

  int sRow[2], sCol[2];
#pragma unroll
  for (int c = 0; c < 2; ++c) {
    int pos = ((c * 4 + w) * 64 + lane) * 8;
    int row = pos >> 6, colE = pos & 63;
    sRow[c] = row;
    sCol[c] = colE ^ ((row & 7) << 3);
  }

  int koff[2][4];
#pragma unroll
  for (int n = 0; n < 2; ++n)
#pragma unroll
    for (int s = 0; s < 4; ++s) {
      int row = n * 32 + l31;
      koff[n][s] = row * 128 + ((s * 32 + hi * 16) ^ ((row & 7) << 4));
    }

  f32x16 zt[2] = {};
  float l_run = 0.f;
  int ntiles = 2 * qt + 2;   // always even

#define STAGE(tt)                                                                  \
  do {                                                                             \
    int kv0 = (tt) * 64;                                                           \
    int kb = ((tt) & 3) << 13;                                                     \
    _Pragma("unroll") for (int c = 0; c < 2; ++c) {                                \
      async16(Kb + (size_t)(kv0 + sRow[c]) * D_ + sCol[c],                         \
              lds + kb + (c * 4 + w) * 1024);                                      \
      async16(VTb + (size_t)sRow[c] * T_ + kv0 + sCol[c],                          \
              lds + 32768 + kb + (c * 4 + w) * 1024);                              \
    }                                                                              \
  } while (0)

  STAGE(0);
  STAGE(1);

#pragma unroll 1
  for (int t = 0; t < ntiles; ++t) {
    if ((t & 1) == 0) {
      __syncthreads();           // drains DMAs for t,t+1; closes reads of t+2,t+3 bufs
      if (t + 2 < ntiles) {
        STAGE(t + 2);
        STAGE(t + 3);
      }
    }
    const char* kbase = lds + ((t & 3) << 13);
    const char* vbase = lds + 32768 + ((t & 3) << 13);

    f32x16 st[2];
    __builtin_amdgcn_s_setprio(1);
#pragma unroll
    for (int n = 0; n < 2; ++n) {
      f32x16 a = {};
#pragma unroll
      for (int s = 0; s < 4; ++s) {
        bf16x8 kf = *(const bf16x8*)(kbase + koff[n][s]);
        a = __builtin_amdgcn_mfma_f32_32x32x16_bf16(kf, qf[s], a, 0, 0, 0);
      }
      st[n] = a;
    }
    __builtin_amdgcn_s_setprio(0);

    if (t >= 2 * qt) {  // diagonal 128-pair: mask kv > qrow
      int kvb = t * 64;
#pragma unroll
      for (int n = 0; n < 2; ++n)
#pragma unroll
        for (int m = 0; m < 4; ++m)
#pragma unroll
          for (int c2 = 0; c2 < 4; ++c2) {
            int kv = kvb + n * 32 + m * 8 + hi * 4 + c2;
            if (kv > qrow) st[n][m * 4 + c2] = -1e30f;
          }
    }

    bf16x8 pb[4];
#pragma unroll
    for (int n = 0; n < 2; ++n) {
      float u[16];
#pragma unroll
      for (int r = 0; r < 16; ++r) {
        u[r] = __builtin_amdgcn_exp2f(st[n][r]);
        l_run += u[r];
      }
#pragma unroll
      for (int hf = 0; hf < 2; ++hf) {
        unsigned int A0, A1, B0, B1;
        asm("v_cvt_pk_bf16_f32 %0, %1, %2" : "=v"(A0) : "v"(u[hf*8+0]), "v"(u[hf*8+1]));
        asm("v_cvt_pk_bf16_f32 %0, %1, %2" : "=v"(A1) : "v"(u[hf*8+2]), "v"(u[hf*8+3]));
        asm("v_cvt_pk_bf16_f32 %0, %1, %2" : "=v"(B0) : "v"(u[hf*8+4]), "v"(u[hf*8+5]));
        asm("v_cvt_pk_bf16_f32 %0, %1, %2" : "=v"(B1) : "v"(u[hf*8+6]), "v"(u[hf*8+7]));
        asm("v_permlane32_swap_b32 %0, %1" : "+v"(A0), "+v"(B0));
        asm("v_permlane32_swap_b32 %0, %1" : "+v"(A1), "+v"(B1));
        u32x4 pk; pk[0] = A0; pk[1] = A1; pk[2] = B0; pk[3] = B1;
        pb[n * 2 + hf] = __builtin_bit_cast(bf16x8, pk);
      }
    }

    __builtin_amdgcn_s_setprio(1);
#pragma unroll
    for (int dt = 0; dt < 2; ++dt) {
#pragma unroll
      for (int s = 0; s < 4; ++s) {
        bf16x8 vf = *(const bf16x8*)(vbase + koff[dt][s]);
        zt[dt] = __builtin_amdgcn_mfma_f32_32x32x16_bf16(vf, pb[s], zt[dt], 0, 0, 0);
      }
    }
    __builtin_amdgcn_s_setprio(0);
  }
#undef STAGE

  l_run += __shfl_xor(l_run, 32);
  float inv = __builtin_amdgcn_rcpf(l_run);
  unsigned short* Zrow = Z + (size_t)(b * T_ + qrow) * D_ + h * DH_;
#pragma unroll
  for (int dt = 0; dt < 2; ++dt)
#pragma unroll
    for (int m = 0; m < 4; ++m) {
      ushort4 o;
      o.x = f2bf(zt[dt][m * 4 + 0] * inv);
      o.y = f2bf(zt[dt][m * 4 + 1] * inv);
      o.z = f2bf(zt[dt][m * 4 + 2] * inv);
      o.w = f2bf(zt[dt][m * 4 + 3] * inv);
      *(ushort4*)(Zrow + dt * 32 + m * 8 + hi * 4) = o;  // d = 32dt + 8m + 4hi + c
    }
}

// ---------------------------------------------------------------- launcher
extern "C" void kernel_launch(void* const* d_in, const int* in_sizes, int n_in,
                              void* d_out, int out_size, void* d_ws, size_t ws_size,
                              hipStream_t stream) {
  (void)in_sizes; (void)n_in; (void)out_size; (void)ws_size;
  const float* x  = (const float*)d_in[0];
  const float* wq = (const float*)d_in[1];
  const float* bq = (const float*)d_in[2];
  const float* wk = (const float*)d_in[3];
  const float* bk = (const float*)d_in[4];
  const float* wv = (const float*)d_in[5];
  const float* bv = (const float*)d_in[6];
  const float* wo = (const float*)d_in[7];
  const float* bo = (const float*)d_in[8];

  char* ws = (char*)d_ws;
  const size_t XB = (size_t)M_ * D_ * 2;   // 12.58 MB
  const size_t WB = (size_t)D_ * D_ * 2;   // 1.18 MB
  unsigned short* xb  = (unsigned short*)(ws);
  unsigned short* wqb = (unsigned short*)(ws + XB);
  unsigned short* wkb = (unsigned short*)(ws + XB + WB);
  unsigned short* wvb = (unsigned short*)(ws + XB + 2 * WB);
  unsigned short* wob = (unsigned short*)(ws + XB + 3 * WB);
  unsigned short* Qb  = (unsigned short*)(ws + XB + 4 * WB);
  unsigned short* Kb  = (unsigned short*)(ws + XB + 4 * WB + XB);
  unsigned short* VTb = (unsigned short*)(ws + XB + 4 * WB + 2 * XB);
  unsigned short* Zb  = xb;  // alias: x dead after projections

  const float SCALE_Q = 0.125f * 1.44269504f;  // fold 1/sqrt(64) and log2(e) into Q

  cvt_kernel<<<dim3(1024, 5), 256, 0, stream>>>(x, wq, wk, wv, wo, xb, wqb, wkb, wvb, wob);
  // fused QKV projections (N=2304 as 9 x 256-col tiles); Q prescaled; V writes V^T.
  gemm_kernel<<<dim3(576), 512, 0, stream>>>(
      xb, wqb, wkb, wvb, bq, bk, bv, Qb, Kb, VTb, SCALE_Q, D_, 1);
  // attn: 768 blocks = 48 heads x 16 q-tiles (q=128 each), desc-qt within XCD
  attn_kernel<<<dim3(768), 256, 0, stream>>>(Qb, Kb, VTb, Zb);
  // out projection -> fp32 d_out. grid 192.
  gemm_kernel<<<dim3(192), 512, 0, stream>>>(
      Zb, wob, wob, wob, bo, bo, bo, d_out, d_out, d_out, 1.0f, D_, 0);
}